// Round 6
// baseline (472.620 us; speedup 1.0000x reference)
//
#include <hip/hip_runtime.h>
#include <math.h>

#define Bc 8
#define Sc 512
#define Hc 512
#define NHc 8
#define HDc 64
#define DISc 32
#define S2c 1024

typedef __attribute__((ext_vector_type(8))) short bf16x8;
typedef __attribute__((ext_vector_type(4))) float f32x4;
#define MFMA16(a, b, c) __builtin_amdgcn_mfma_f32_16x16x32_bf16(a, b, c, 0, 0, 0)

__device__ __forceinline__ unsigned short f2bf(float f) {
  unsigned u = __float_as_uint(f);
  return (unsigned short)((u + 0x7fffu + ((u >> 16) & 1u)) >> 16);  // RNE
}
__device__ __forceinline__ float b2f(unsigned short u) {
  return __uint_as_float((unsigned)u << 16);
}
__device__ __forceinline__ bf16x8 ldb16x8(const unsigned short* p) {
  union { uint4 u; bf16x8 s; } cv;
  cv.u = *(const uint4*)p;
  return cv.s;
}

// ---------------------------------------------------------------------------
// fp32 -> bf16 conversions for x, Wq, Wk, Wv, Wo (one fused launch).
// ---------------------------------------------------------------------------
__global__ __launch_bounds__(256) void cvt5_k(
    const float* __restrict__ x, const float* __restrict__ wq,
    const float* __restrict__ wk, const float* __restrict__ wv,
    const float* __restrict__ wo, unsigned short* __restrict__ x16,
    unsigned short* __restrict__ w16q, unsigned short* __restrict__ w16k,
    unsigned short* __restrict__ w16v, unsigned short* __restrict__ w16o) {
  int i = blockIdx.x * 256 + threadIdx.x;
  const float* src; unsigned short* dst; int off;
  if (i < 524288)      { src = x;  dst = x16;  off = i; }
  else if (i < 589824) { src = wq; dst = w16q; off = i - 524288; }
  else if (i < 720896) { src = wk; dst = w16k; off = i - 589824; }
  else if (i < 851968) { src = wv; dst = w16v; off = i - 720896; }
  else                 { src = wo; dst = w16o; off = i - 851968; }
  float4 v = ((const float4*)src)[off];
  ushort4 u;
  u.x = f2bf(v.x); u.y = f2bf(v.y); u.z = f2bf(v.z); u.w = f2bf(v.w);
  ((ushort4*)dst)[off] = u;
}

// ---------------------------------------------------------------------------
// Pack rel (int32 0..31) + mask (u8) -> u8 (rd | m<<7). 4M elems, 16/thread.
// ---------------------------------------------------------------------------
__global__ __launch_bounds__(256) void pack_k(const int* __restrict__ rel,
                                              const unsigned char* __restrict__ mask,
                                              unsigned char* __restrict__ pk8) {
  int i = blockIdx.x * 256 + threadIdx.x;      // 262144 threads
  const int* rp = rel + i * 16;
  uint4 mu = *(const uint4*)(mask + i * 16);
  const unsigned char* mb = (const unsigned char*)&mu;
  uint4 o;
  unsigned* ow = (unsigned*)&o;
#pragma unroll
  for (int g = 0; g < 4; ++g) {
    int4 r4 = ((const int4*)rp)[g];
    unsigned b0 = ((unsigned)r4.x & 31u) | (mb[g * 4 + 0] ? 0x80u : 0u);
    unsigned b1 = ((unsigned)r4.y & 31u) | (mb[g * 4 + 1] ? 0x80u : 0u);
    unsigned b2 = ((unsigned)r4.z & 31u) | (mb[g * 4 + 2] ? 0x80u : 0u);
    unsigned b3 = ((unsigned)r4.w & 31u) | (mb[g * 4 + 3] ? 0x80u : 0u);
    ow[g] = b0 | (b1 << 8) | (b2 << 16) | (b3 << 24);
  }
  *(uint4*)(pk8 + i * 16) = o;
}

// ---------------------------------------------------------------------------
// bf16 MFMA GEMM: C[M,N] = A16[M,K] @ B16[N,K]^T, fp32 accumulate.
// 64x64 tile, BK=32, block 256 (4 waves 2x2, wave tile 32x32).
// MODE 0: fp32 C | 1: q16h[b][h][s][d] | 2: kb16[b][h][k2][d] | 3: vT16[b][h][d][k2]
// ---------------------------------------------------------------------------
template <int MODE>
__global__ __launch_bounds__(256, 4) void gemm16_k(
    const unsigned short* __restrict__ A, const unsigned short* __restrict__ B,
    void* __restrict__ outp, int M, int N, int K) {
  const int t = threadIdx.x;
  const int w = t >> 6, lane = t & 63, ln = lane & 15, qd = lane >> 4;
  const int wm = (w >> 1) << 5, wn = (w & 1) << 5;
  const int m0 = blockIdx.y << 6, n0 = blockIdx.x << 6;
  __shared__ unsigned short As[64 * 32];
  __shared__ unsigned short Bs[64 * 32];
  f32x4 z = {0.f, 0.f, 0.f, 0.f};
  f32x4 acc[2][2] = {{z, z}, {z, z}};
  const int srow = t >> 2, sc8 = (t & 3) << 3;
  for (int k0 = 0; k0 < K; k0 += 32) {
    *(uint4*)&As[srow * 32 + sc8] = *(const uint4*)(A + (size_t)(m0 + srow) * K + k0 + sc8);
    *(uint4*)&Bs[srow * 32 + sc8] = *(const uint4*)(B + (size_t)(n0 + srow) * K + k0 + sc8);
    __syncthreads();
    bf16x8 a0 = ldb16x8(&As[(wm + ln) * 32 + qd * 8]);
    bf16x8 a1 = ldb16x8(&As[(wm + 16 + ln) * 32 + qd * 8]);
    bf16x8 b0 = ldb16x8(&Bs[(wn + ln) * 32 + qd * 8]);
    bf16x8 b1 = ldb16x8(&Bs[(wn + 16 + ln) * 32 + qd * 8]);
    acc[0][0] = MFMA16(a0, b0, acc[0][0]);
    acc[0][1] = MFMA16(a0, b1, acc[0][1]);
    acc[1][0] = MFMA16(a1, b0, acc[1][0]);
    acc[1][1] = MFMA16(a1, b1, acc[1][1]);
    __syncthreads();
  }
#pragma unroll
  for (int tm = 0; tm < 2; ++tm)
#pragma unroll
    for (int tn = 0; tn < 2; ++tn)
#pragma unroll
      for (int r = 0; r < 4; ++r) {
        int m = m0 + wm + tm * 16 + qd * 4 + r;
        int n = n0 + wn + tn * 16 + ln;
        float v = acc[tm][tn][r];
        if (MODE == 0) {
          ((float*)outp)[(size_t)m * N + n] = v;
        } else {
          int bb = m >> 9, s = m & 511, hh = (n >> 6) & 7, d = n & 63;
          if (MODE == 1)
            ((unsigned short*)outp)[((size_t)(bb * 8 + hh) * 512 + s) * 64 + d] = f2bf(v);
          else if (MODE == 2) {
            int k2 = 2 * s + (n >> 9);
            ((unsigned short*)outp)[((size_t)(bb * 8 + hh) * 1024 + k2) * 64 + d] = f2bf(v);
          } else {
            int k2 = 2 * s + (n >> 9);
            ((unsigned short*)outp)[((size_t)(bb * 8 + hh) * 64 + d) * 1024 + k2] = f2bf(v);
          }
        }
      }
}

// ---------------------------------------------------------------------------
// Pos-weight tables from bf16 h-major rows.
// ---------------------------------------------------------------------------
__global__ __launch_bounds__(256) void posw16_k(const unsigned short* __restrict__ rows16,
                                                const float* __restrict__ emb,
                                                float* __restrict__ out, int R) {
  const int t = threadIdx.x;
  const int tiles = R >> 6;
  const int rt = blockIdx.x % tiles;
  const int h = (blockIdx.x / tiles) & 7;
  const int b = blockIdx.x / (tiles * 8);
  __shared__ float es[32][65];
  __shared__ float xs[64][65];
#pragma unroll
  for (int i = 0; i < 2; ++i) {
    int f = t + (i << 8);
    int n = f >> 4, d4 = (f & 15) << 2;
    float4 v4 = *(const float4*)(emb + ((size_t)n << 9) + (h << 6) + d4);
    es[n][d4] = v4.x; es[n][d4 + 1] = v4.y; es[n][d4 + 2] = v4.z; es[n][d4 + 3] = v4.w;
  }
  const size_t row0 = (size_t)(b * 8 + h) * R + (rt << 6);
#pragma unroll
  for (int p = 0; p < 2; ++p) {
    int id = t + (p << 8);
    int r = id >> 3, c8 = (id & 7) << 3;
    uint4 u4 = *(const uint4*)(rows16 + (row0 + r) * 64 + c8);
    const unsigned short* us = (const unsigned short*)&u4;
#pragma unroll
    for (int j = 0; j < 8; ++j) xs[r][c8 + j] = b2f(us[j]);
  }
  __syncthreads();
  const int n = t & 31;
  const int rs0 = (t >> 5) << 3;
  for (int rr = 0; rr < 8; ++rr) {
    float s = 0.f;
#pragma unroll
    for (int d = 0; d < 64; ++d) s = fmaf(xs[rs0 + rr][d], es[n][d], s);
    out[((((size_t)b * 8 + h) * R) + (rt << 6) + rs0 + rr) * 32 + n] = s;
  }
}

// ---------------------------------------------------------------------------
// Pass 1: dense bias matrix. pbias[bl,h,q,k] = bf16(qpw[q][rd] + kpw[k][rd]),
// masked -> bf16 -inf. Block = (bl,h,kt64,qc128). Pure gather+stream.
// grid 2048, 256 thr, LDS ~22 KB.
// ---------------------------------------------------------------------------
__global__ __launch_bounds__(256) void bias_k(
    const float* __restrict__ qpw, const float* __restrict__ kpw,
    const unsigned char* __restrict__ pk8, unsigned short* __restrict__ pbias,
    int b0) {
  const int bid = blockIdx.x;
  const int bl = bid & 3, h = (bid >> 2) & 7, kt = (bid >> 5) & 15, qc = bid >> 9;
  const int b = b0 + bl;
  const int q0 = qc << 7, kt0 = kt << 6;
  const int t = threadIdx.x;
  __shared__ unsigned char pkt[128 * 64];
  __shared__ unsigned short q32t[128 * 36];
  __shared__ unsigned short kpwt[64 * 36];
#pragma unroll
  for (int p = 0; p < 2; ++p) {            // pkt: 512 uint4
    int idx = t + (p << 8);
    int row = idx >> 2, c16 = (idx & 3) << 4;
    *(uint4*)&pkt[row * 64 + c16] =
        *(const uint4*)(pk8 + ((size_t)(b * 512) + q0 + row) * 1024 + kt0 + c16);
  }
#pragma unroll
  for (int p = 0; p < 4; ++p) {            // q32t: 1024 float4 -> bf16
    int idx = t + (p << 8);
    int row = idx >> 3, c4 = (idx & 7) << 2;
    float4 v = *(const float4*)(qpw + ((size_t)((b * 8 + h) * 512) + q0 + row) * 32 + c4);
    ushort4 u;
    u.x = f2bf(v.x); u.y = f2bf(v.y); u.z = f2bf(v.z); u.w = f2bf(v.w);
    *(ushort4*)&q32t[row * 36 + c4] = u;
  }
#pragma unroll
  for (int p = 0; p < 2; ++p) {            // kpwt: 512 float4 -> bf16
    int idx = t + (p << 8);
    int row = idx >> 3, c4 = (idx & 7) << 2;
    float4 v = *(const float4*)(kpw + ((size_t)((b * 8 + h) * 1024) + kt0 + row) * 32 + c4);
    ushort4 u;
    u.x = f2bf(v.x); u.y = f2bf(v.y); u.z = f2bf(v.z); u.w = f2bf(v.w);
    *(ushort4*)&kpwt[row * 36 + c4] = u;
  }
  __syncthreads();
  const int k = t & 63, qg = t >> 6;
  unsigned short* obase = pbias + (((size_t)((bl * 8 + h) * 512) + q0) * 1024) + kt0 + k;
#pragma unroll
  for (int it = 0; it < 32; ++it) {
    int q = qg + (it << 2);
    unsigned pm = pkt[q * 64 + k];
    int rd = pm & 31;
    float s = b2f(q32t[q * 36 + rd]) + b2f(kpwt[k * 36 + rd]);
    unsigned short o = (pm & 0x80u) ? (unsigned short)0xFF80 : f2bf(s);
    obase[(size_t)q * 1024] = o;
  }
}

// ---------------------------------------------------------------------------
// Pass 2: P' = exp((QK^T + bias)/8), in-place over pbias. Zero barriers,
// zero gathers, zero atomics. Block = 128 thr = 2 independent 16-q waves;
// each wave owns its LDS tile end-to-end. grid 2048 -> ~16 waves/CU.
// ---------------------------------------------------------------------------
__global__ __launch_bounds__(128) void qkexp_k(
    const unsigned short* __restrict__ q16h, const unsigned short* __restrict__ kb16,
    unsigned short* __restrict__ pbias, int b0) {
  const int bid = blockIdx.x;
  const int bl = bid & 3, h = (bid >> 2) & 7, qt = (bid >> 5) & 15, ks = bid >> 9;
  const int b = b0 + bl;
  const int q0 = qt << 5;
  const int t = threadIdx.x;
  const int w = t >> 6, lane = t & 63, ln = lane & 15, qd = lane >> 4;
  __shared__ unsigned short Bs[2][16 * 72];
  const unsigned short* kbase = kb16 + (size_t)(b * 8 + h) * 65536;
  bf16x8 aQ0, aQ1;
  {
    const unsigned short* qsrc =
        q16h + ((size_t)((b * 8 + h) * 512) + q0 + w * 16 + ln) * 64;
    aQ0 = ldb16x8(qsrc + qd * 8);
    aQ1 = ldb16x8(qsrc + 32 + qd * 8);
  }
  const int rr = lane >> 2, c0 = (lane & 3) << 3;
  unsigned short* pb_row =
      pbias + ((size_t)((bl * 8 + h) * 512) + q0 + w * 16 + rr) * 1024;
  f32x4 z = {0.f, 0.f, 0.f, 0.f};
  for (int kti = ks * 4; kti < ks * 4 + 4; ++kti) {
    const int kt0 = kti << 6;
    *(uint4*)&Bs[w][rr * 72 + c0]      = *(const uint4*)(pb_row + kt0 + c0);
    *(uint4*)&Bs[w][rr * 72 + c0 + 32] = *(const uint4*)(pb_row + kt0 + c0 + 32);
    f32x4 sc4[4];
#pragma unroll
    for (int t4 = 0; t4 < 4; ++t4) {
      f32x4 c = z;
      c = MFMA16(aQ0, ldb16x8(kbase + (size_t)(kt0 + t4 * 16 + ln) * 64 + qd * 8), c);
      c = MFMA16(aQ1, ldb16x8(kbase + (size_t)(kt0 + t4 * 16 + ln) * 64 + 32 + qd * 8), c);
      sc4[t4] = c;
    }
#pragma unroll
    for (int r = 0; r < 4; ++r)
#pragma unroll
      for (int t4 = 0; t4 < 4; ++t4) {
        int idx = (qd * 4 + r) * 72 + t4 * 16 + ln;
        float p = __expf((sc4[t4][r] + b2f(Bs[w][idx])) * 0.125f);
        Bs[w][idx] = f2bf(p);
      }
    *(uint4*)(pb_row + kt0 + c0)      = *(const uint4*)&Bs[w][rr * 72 + c0];
    *(uint4*)(pb_row + kt0 + c0 + 32) = *(const uint4*)&Bs[w][rr * 72 + c0 + 32];
  }
}

// ---------------------------------------------------------------------------
// Pass 3: unnormalized O1 = P' @ V (fp32 out). Block = 16 q x split-K-4
// (4 waves), LDS combine. grid 1024/chunk.
// ---------------------------------------------------------------------------
__global__ __launch_bounds__(256) void pv_k(
    const unsigned short* __restrict__ pbias, const unsigned short* __restrict__ vT16,
    float* __restrict__ attnf, int b0) {
  const int bid = blockIdx.x;
  const int bl = bid & 3, h = (bid >> 2) & 7, qt = bid >> 5;    // 0..31
  const int b = b0 + bl;
  const int q0 = qt << 4;
  const int t = threadIdx.x;
  const int g = t >> 6, lane = t & 63, ln = lane & 15, qd = lane >> 4;
  __shared__ float accb[3][16 * 64];
  const unsigned short* vbase = vT16 + (size_t)(b * 8 + h) * 65536;
  const unsigned short* pbase =
      pbias + ((size_t)((bl * 8 + h) * 512) + q0 + ln) * 1024;
  f32x4 z = {0.f, 0.f, 0.f, 0.f};
  f32x4 acc[4] = {z, z, z, z};
  for (int kti = g * 4; kti < g * 4 + 4; ++kti) {
    const int kt0 = kti << 6;
    bf16x8 a0 = ldb16x8(pbase + kt0 + qd * 8);
    bf16x8 a1 = ldb16x8(pbase + kt0 + 32 + qd * 8);
#pragma unroll
    for (int dt = 0; dt < 4; ++dt) {
      acc[dt] = MFMA16(a0, ldb16x8(vbase + (size_t)(dt * 16 + ln) * 1024 + kt0 + qd * 8), acc[dt]);
      acc[dt] = MFMA16(a1, ldb16x8(vbase + (size_t)(dt * 16 + ln) * 1024 + kt0 + 32 + qd * 8), acc[dt]);
    }
  }
  if (g > 0) {
#pragma unroll
    for (int r = 0; r < 4; ++r)
#pragma unroll
      for (int dt = 0; dt < 4; ++dt)
        accb[g - 1][(qd * 4 + r) * 64 + dt * 16 + ln] = acc[dt][r];
  }
  __syncthreads();
  if (g == 0) {
    float* obase = attnf + ((size_t)(b * 512) + q0 + qd * 4) * 512 + (h << 6);
#pragma unroll
    for (int r = 0; r < 4; ++r)
#pragma unroll
      for (int dt = 0; dt < 4; ++dt) {
        float v = acc[dt][r];
#pragma unroll
        for (int gg = 0; gg < 3; ++gg)
          v += accb[gg][(qd * 4 + r) * 64 + dt * 16 + ln];
        obase[(size_t)r * 512 + dt * 16 + ln] = v;
      }
  }
}

// ---------------------------------------------------------------------------
// Pass 4: vdw histogram (LDS ds_add_f32, bank-spread pad-33), l = row-sum,
// O = (O1 + vdw@v_emb)/l -> bf16 attn16. Block = (bl,h,32q). grid 512/chunk.
// ---------------------------------------------------------------------------
__global__ __launch_bounds__(256) void vdw_k(
    const unsigned short* __restrict__ pbias, const unsigned char* __restrict__ pk8,
    const float* __restrict__ attnf, const float* __restrict__ vpe,
    unsigned short* __restrict__ attn16, int b0) {
  const int bid = blockIdx.x;
  const int bl = bid & 3, h = (bid >> 2) & 7, qt = bid >> 5;    // 0..15
  const int b = b0 + bl;
  const int q0 = qt << 5;
  const int t = threadIdx.x;
  const int w = t >> 6, lane = t & 63;
  __shared__ float vdwa[32 * 33];
  __shared__ float vembs[32 * 68];
  for (int i = t; i < 32 * 33; i += 256) vdwa[i] = 0.f;
#pragma unroll
  for (int p = 0; p < 2; ++p) {
    int idx = t + (p << 8);
    int row = idx >> 4, c4 = (idx & 15) << 2;
    *(float4*)&vembs[row * 68 + c4] =
        *(const float4*)(vpe + ((size_t)row << 9) + (h << 6) + c4);
  }
  __syncthreads();
#pragma unroll
  for (int j = 0; j < 8; ++j) {
    int ql = (w << 3) + j;
    const unsigned short* prow =
        pbias + ((size_t)((bl * 8 + h) * 512) + q0 + ql) * 1024;
    const unsigned char* krow = pk8 + ((size_t)(b * 512) + q0 + ql) * 1024;
#pragma unroll
    for (int p2 = 0; p2 < 2; ++p2) {
      int k0 = (p2 << 9) + (lane << 3);
      uint4 pv4 = *(const uint4*)(prow + k0);
      uint2 rb = *(const uint2*)(krow + k0);
      const unsigned short* pu = (const unsigned short*)&pv4;
      const unsigned char* ru = (const unsigned char*)&rb;
#pragma unroll
      for (int e = 0; e < 8; ++e)
        atomicAdd(&vdwa[ql * 33 + (ru[e] & 31)], b2f(pu[e]));   // masked p==0
    }
  }
  __syncthreads();
  const int d = t & 63, qg = t >> 6;
#pragma unroll
  for (int j = 0; j < 8; ++j) {
    int ql = (qg << 3) + j;
    float l = 0.f, o2 = 0.f;
#pragma unroll
    for (int n = 0; n < 32; ++n) {
      float v = vdwa[ql * 33 + n];
      l += v;
      o2 = fmaf(v, vembs[n * 68 + d], o2);
    }
    size_t oi = ((size_t)(b * 512) + q0 + ql) * 512 + (h << 6) + d;
    attn16[oi] = f2bf((attnf[oi] + o2) / l);
  }
}

// ---------------------------------------------------------------------------
extern "C" void kernel_launch(void* const* d_in, const int* in_sizes, int n_in,
                              void* d_out, int out_size, void* d_ws, size_t ws_size,
                              hipStream_t stream) {
  const float* x = (const float*)d_in[0];
  const int* rel = (const int*)d_in[1];
  const unsigned char* mask = (const unsigned char*)d_in[2];
  const float* qpe = (const float*)d_in[3];
  const float* kpe = (const float*)d_in[4];
  const float* vpe = (const float*)d_in[5];
  const float* Wq = (const float*)d_in[6];
  const float* Wk = (const float*)d_in[7];
  const float* Wv = (const float*)d_in[8];
  const float* Wo = (const float*)d_in[9];
  float* out = (float*)d_out;

  float* ws = (float*)d_ws;
  float* qpw = ws;                                   // 1,048,576 f
  float* kpw = qpw + 1048576;                        // 2,097,152 f
  unsigned short* kb16 = (unsigned short*)(kpw + 2097152);   // 4,194,304 u16
  unsigned short* vT16 = kb16 + 4194304;             // 4,194,304 u16
  unsigned short* q16h = vT16 + 4194304;             // 2,097,152 u16
  unsigned short* attn16 = q16h + 2097152;           // 2,097,152 u16
  unsigned short* x16 = attn16 + 2097152;            // 2,097,152 u16
  unsigned short* w16q = x16 + 2097152;              //   262,144 u16
  unsigned short* w16k = w16q + 262144;              //   524,288 u16
  unsigned short* w16v = w16k + 524288;              //   524,288 u16
  unsigned short* w16o = w16v + 524288;              //   262,144 u16
  unsigned char* pk8 = (unsigned char*)(w16o + 262144);      // 4 MB
  float* attnf = (float*)(pk8 + 4194304);            // 2,097,152 f (8 MB)
  unsigned short* pbias = (unsigned short*)(attnf + 2097152);// 16,777,216 u16 (32 MB)
                                                     // total ~91 MB

  pack_k<<<1024, 256, 0, stream>>>(rel, mask, pk8);
  cvt5_k<<<3584, 256, 0, stream>>>(x, Wq, Wk, Wv, Wo, x16, w16q, w16k, w16v, w16o);
  gemm16_k<1><<<dim3(8, 64), 256, 0, stream>>>(x16, w16q, q16h, 4096, 512, 512);
  gemm16_k<2><<<dim3(16, 64), 256, 0, stream>>>(x16, w16k, kb16, 4096, 1024, 512);
  gemm16_k<3><<<dim3(16, 64), 256, 0, stream>>>(x16, w16v, vT16, 4096, 1024, 512);
  posw16_k<<<8 * 8 * 8, 256, 0, stream>>>(q16h, qpe, qpw, 512);
  posw16_k<<<8 * 8 * 16, 256, 0, stream>>>(kb16, kpe, kpw, 1024);
  for (int ch = 0; ch < 2; ++ch) {
    int b0 = ch * 4;
    bias_k<<<2048, 256, 0, stream>>>(qpw, kpw, pk8, pbias, b0);
    qkexp_k<<<2048, 128, 0, stream>>>(q16h, kb16, pbias, b0);
    pv_k<<<1024, 256, 0, stream>>>(pbias, vT16, attnf, b0);
    vdw_k<<<512, 256, 0, stream>>>(pbias, pk8, attnf, vpe, attn16, b0);
  }
  gemm16_k<0><<<dim3(8, 64), 256, 0, stream>>>(attn16, w16o, out, 4096, 512, 512);
}

// Round 7
// 238.115 us; speedup vs baseline: 1.9848x; 1.9848x over previous
//
#include <hip/hip_runtime.h>
#include <math.h>

#define Bc 8
#define Sc 512
#define Hc 512
#define NHc 8
#define HDc 64
#define DISc 32
#define S2c 1024

typedef __attribute__((ext_vector_type(8))) short bf16x8;
typedef __attribute__((ext_vector_type(4))) float f32x4;
#define MFMA16(a, b, c) __builtin_amdgcn_mfma_f32_16x16x32_bf16(a, b, c, 0, 0, 0)

__device__ __forceinline__ unsigned short f2bf(float f) {
  unsigned u = __float_as_uint(f);
  return (unsigned short)((u + 0x7fffu + ((u >> 16) & 1u)) >> 16);  // RNE
}
__device__ __forceinline__ float b2f(unsigned short u) {
  return __uint_as_float((unsigned)u << 16);
}
__device__ __forceinline__ bf16x8 ldb16x8(const unsigned short* p) {
  union { uint4 u; bf16x8 s; } cv;
  cv.u = *(const uint4*)p;
  return cv.s;
}

// ---------------------------------------------------------------------------
// fp32 -> bf16 conversions for x, Wq, Wk, Wv, Wo (one fused launch).
// ---------------------------------------------------------------------------
__global__ __launch_bounds__(256) void cvt5_k(
    const float* __restrict__ x, const float* __restrict__ wq,
    const float* __restrict__ wk, const float* __restrict__ wv,
    const float* __restrict__ wo, unsigned short* __restrict__ x16,
    unsigned short* __restrict__ w16q, unsigned short* __restrict__ w16k,
    unsigned short* __restrict__ w16v, unsigned short* __restrict__ w16o) {
  int i = blockIdx.x * 256 + threadIdx.x;
  const float* src; unsigned short* dst; int off;
  if (i < 524288)      { src = x;  dst = x16;  off = i; }
  else if (i < 589824) { src = wq; dst = w16q; off = i - 524288; }
  else if (i < 720896) { src = wk; dst = w16k; off = i - 589824; }
  else if (i < 851968) { src = wv; dst = w16v; off = i - 720896; }
  else                 { src = wo; dst = w16o; off = i - 851968; }
  float4 v = ((const float4*)src)[off];
  ushort4 u;
  u.x = f2bf(v.x); u.y = f2bf(v.y); u.z = f2bf(v.z); u.w = f2bf(v.w);
  ((ushort4*)dst)[off] = u;
}

// ---------------------------------------------------------------------------
// Pack rel (int32 0..31) + mask (u8) -> u8 (rd | m<<7). 4M elems, 16/thread.
// ---------------------------------------------------------------------------
__global__ __launch_bounds__(256) void pack_k(const int* __restrict__ rel,
                                              const unsigned char* __restrict__ mask,
                                              unsigned char* __restrict__ pk8) {
  int i = blockIdx.x * 256 + threadIdx.x;      // 262144 threads
  const int* rp = rel + i * 16;
  uint4 mu = *(const uint4*)(mask + i * 16);
  const unsigned char* mb = (const unsigned char*)&mu;
  uint4 o;
  unsigned* ow = (unsigned*)&o;
#pragma unroll
  for (int g = 0; g < 4; ++g) {
    int4 r4 = ((const int4*)rp)[g];
    unsigned b0 = ((unsigned)r4.x & 31u) | (mb[g * 4 + 0] ? 0x80u : 0u);
    unsigned b1 = ((unsigned)r4.y & 31u) | (mb[g * 4 + 1] ? 0x80u : 0u);
    unsigned b2 = ((unsigned)r4.z & 31u) | (mb[g * 4 + 2] ? 0x80u : 0u);
    unsigned b3 = ((unsigned)r4.w & 31u) | (mb[g * 4 + 3] ? 0x80u : 0u);
    ow[g] = b0 | (b1 << 8) | (b2 << 16) | (b3 << 24);
  }
  *(uint4*)(pk8 + i * 16) = o;
}

// ---------------------------------------------------------------------------
// bf16 MFMA GEMM: C[M,N] = A16[M,K] @ B16[N,K]^T, fp32 accumulate.
// 64x64 tile, BK=32, block 256 (4 waves 2x2, wave tile 32x32).
// MODE 0: fp32 C | 1: q16h[b][h][s][d] | 2: kb16[b][h][k2][d] | 3: vT16[b][h][d][k2]
// ---------------------------------------------------------------------------
template <int MODE>
__global__ __launch_bounds__(256, 4) void gemm16_k(
    const unsigned short* __restrict__ A, const unsigned short* __restrict__ B,
    void* __restrict__ outp, int M, int N, int K) {
  const int t = threadIdx.x;
  const int w = t >> 6, lane = t & 63, ln = lane & 15, qd = lane >> 4;
  const int wm = (w >> 1) << 5, wn = (w & 1) << 5;
  const int m0 = blockIdx.y << 6, n0 = blockIdx.x << 6;
  __shared__ unsigned short As[64 * 32];
  __shared__ unsigned short Bs[64 * 32];
  f32x4 z = {0.f, 0.f, 0.f, 0.f};
  f32x4 acc[2][2] = {{z, z}, {z, z}};
  const int srow = t >> 2, sc8 = (t & 3) << 3;
  for (int k0 = 0; k0 < K; k0 += 32) {
    *(uint4*)&As[srow * 32 + sc8] = *(const uint4*)(A + (size_t)(m0 + srow) * K + k0 + sc8);
    *(uint4*)&Bs[srow * 32 + sc8] = *(const uint4*)(B + (size_t)(n0 + srow) * K + k0 + sc8);
    __syncthreads();
    bf16x8 a0 = ldb16x8(&As[(wm + ln) * 32 + qd * 8]);
    bf16x8 a1 = ldb16x8(&As[(wm + 16 + ln) * 32 + qd * 8]);
    bf16x8 b0 = ldb16x8(&Bs[(wn + ln) * 32 + qd * 8]);
    bf16x8 b1 = ldb16x8(&Bs[(wn + 16 + ln) * 32 + qd * 8]);
    acc[0][0] = MFMA16(a0, b0, acc[0][0]);
    acc[0][1] = MFMA16(a0, b1, acc[0][1]);
    acc[1][0] = MFMA16(a1, b0, acc[1][0]);
    acc[1][1] = MFMA16(a1, b1, acc[1][1]);
    __syncthreads();
  }
#pragma unroll
  for (int tm = 0; tm < 2; ++tm)
#pragma unroll
    for (int tn = 0; tn < 2; ++tn)
#pragma unroll
      for (int r = 0; r < 4; ++r) {
        int m = m0 + wm + tm * 16 + qd * 4 + r;
        int n = n0 + wn + tn * 16 + ln;
        float v = acc[tm][tn][r];
        if (MODE == 0) {
          ((float*)outp)[(size_t)m * N + n] = v;
        } else {
          int bb = m >> 9, s = m & 511, hh = (n >> 6) & 7, d = n & 63;
          if (MODE == 1)
            ((unsigned short*)outp)[((size_t)(bb * 8 + hh) * 512 + s) * 64 + d] = f2bf(v);
          else if (MODE == 2) {
            int k2 = 2 * s + (n >> 9);
            ((unsigned short*)outp)[((size_t)(bb * 8 + hh) * 1024 + k2) * 64 + d] = f2bf(v);
          } else {
            int k2 = 2 * s + (n >> 9);
            ((unsigned short*)outp)[((size_t)(bb * 8 + hh) * 64 + d) * 1024 + k2] = f2bf(v);
          }
        }
      }
}

// ---------------------------------------------------------------------------
// Pos-weight tables from bf16 h-major rows.
// ---------------------------------------------------------------------------
__global__ __launch_bounds__(256) void posw16_k(const unsigned short* __restrict__ rows16,
                                                const float* __restrict__ emb,
                                                float* __restrict__ out, int R) {
  const int t = threadIdx.x;
  const int tiles = R >> 6;
  const int rt = blockIdx.x % tiles;
  const int h = (blockIdx.x / tiles) & 7;
  const int b = blockIdx.x / (tiles * 8);
  __shared__ float es[32][65];
  __shared__ float xs[64][65];
#pragma unroll
  for (int i = 0; i < 2; ++i) {
    int f = t + (i << 8);
    int n = f >> 4, d4 = (f & 15) << 2;
    float4 v4 = *(const float4*)(emb + ((size_t)n << 9) + (h << 6) + d4);
    es[n][d4] = v4.x; es[n][d4 + 1] = v4.y; es[n][d4 + 2] = v4.z; es[n][d4 + 3] = v4.w;
  }
  const size_t row0 = (size_t)(b * 8 + h) * R + (rt << 6);
#pragma unroll
  for (int p = 0; p < 2; ++p) {
    int id = t + (p << 8);
    int r = id >> 3, c8 = (id & 7) << 3;
    uint4 u4 = *(const uint4*)(rows16 + (row0 + r) * 64 + c8);
    const unsigned short* us = (const unsigned short*)&u4;
#pragma unroll
    for (int j = 0; j < 8; ++j) xs[r][c8 + j] = b2f(us[j]);
  }
  __syncthreads();
  const int n = t & 31;
  const int rs0 = (t >> 5) << 3;
  for (int rr = 0; rr < 8; ++rr) {
    float s = 0.f;
#pragma unroll
    for (int d = 0; d < 64; ++d) s = fmaf(xs[rs0 + rr][d], es[n][d], s);
    out[((((size_t)b * 8 + h) * R) + (rt << 6) + rs0 + rr) * 32 + n] = s;
  }
}

// ---------------------------------------------------------------------------
// MFMA attention (R5 structure) with the vdw histogram in FIXED-POINT u64:
// LDS float atomicAdd lowers to a CAS retry loop (~300 dependent cycles each,
// the R3-R6 mystery stall); atomicAdd(u64) is native ds_add_u64. p scaled by
// 2^26: p<=e^9~8100 -> p*Q<2^39, x1024 terms < 2^49, no overflow; trunc error
// 2^-26/term, invisible vs bf16. XCD-swizzled grid (bid%8==b), split-K waves.
// ---------------------------------------------------------------------------
__global__ __launch_bounds__(512, 4) void attn5_k(
    const unsigned short* __restrict__ q16h, const unsigned short* __restrict__ kb16,
    const unsigned short* __restrict__ vT16, const float* __restrict__ qpw,
    const float* __restrict__ kpw, const unsigned char* __restrict__ pk8,
    const float* __restrict__ v_emb, unsigned short* __restrict__ attn16) {
  const int bid = blockIdx.x;
  const int b = bid & 7;                 // XCD-affine: bid%8 == b
  const int h = (bid >> 3) & 7;
  const int qb = ((bid >> 6) & 7) << 6;
  const int t = threadIdx.x;
  const int w = t >> 6;
  const int g = w >> 2;
  const int ws4 = w & 3;
  const int lane = t & 63;
  const int ln = lane & 15;
  const int qd = lane >> 4;

  __shared__ __align__(16) char smem[60928];
  unsigned char*  pkt  = (unsigned char*)smem;                // 2 x (64x80) u8
  unsigned short* kpws = (unsigned short*)(smem + 10240);     // 2 x (64x36) u16
  unsigned short* q32s = (unsigned short*)(smem + 19456);     // 64x36 u16
  unsigned short* pbuf = (unsigned short*)(smem + 24064);     // 8 x (16x72) u16
  unsigned long long* vdwm64 = (unsigned long long*)(smem + 42496); // 4 x (16x36) u64
  // endgame aliases (source regions dead by then):
  float*          accbuf = (float*)smem;                      // 4 x (16x68) f (pkt+kpws dead)
  unsigned short* vest   = (unsigned short*)(smem + 24064);   // 64x40 u16 (pbuf dead)
  unsigned short* vdwb   = (unsigned short*)(smem + 29184);   // 4 x (16x40) u16

  for (int i = t; i < 4 * 16 * 36; i += 512) vdwm64[i] = 0ull;
  {  // q32s: 64 q x 32 n, fp32 -> bf16
    const float* src = qpw + ((size_t)((b * 8 + h) * 512 + qb)) * 32;
    int row = t >> 3, c4 = (t & 7) << 2;
    float4 v = *(const float4*)(src + row * 32 + c4);
    ushort4 u;
    u.x = f2bf(v.x); u.y = f2bf(v.y); u.z = f2bf(v.z); u.w = f2bf(v.w);
    *(ushort4*)&q32s[row * 36 + c4] = u;
  }
  const unsigned short* kbase = kb16 + (size_t)(b * 8 + h) * 65536;
  const unsigned short* vbase = vT16 + (size_t)(b * 8 + h) * 65536;
  bf16x8 aQ[2];
  {
    const unsigned short* qsrc =
        q16h + ((size_t)((b * 8 + h) * 512 + qb + ws4 * 16 + ln)) * 64;
    aQ[0] = ldb16x8(qsrc + qd * 8);
    aQ[1] = ldb16x8(qsrc + 32 + qd * 8);
  }
  f32x4 z = {0.f, 0.f, 0.f, 0.f};
  f32x4 acc[4] = {z, z, z, z};

  for (int kti = 0; kti < 8; ++kti) {
    {  // stage: squad (t>>8) stages its kt half: packed rel/mask + kpw
      int u = t & 255, gg = t >> 8;
      int kt0s = (kti + gg * 8) << 6;
      unsigned char* pt_ = pkt + gg * 5120;
      unsigned short* kp_ = kpws + gg * 2304;
      int qr = u >> 2, cg = (u & 3) << 4;
      uint4 pv = *(const uint4*)(pk8 + ((size_t)(b * 512 + qb + qr)) * 1024 + kt0s + cg);
      *(uint4*)&pt_[qr * 80 + cg] = pv;
      int krow = u >> 2, kc8 = (u & 3) << 3;
      const float* kpp = kpw + ((size_t)((b * 8 + h) * 1024) + kt0s + krow) * 32 + kc8;
      float4 f0 = *(const float4*)kpp;
      float4 f1 = *(const float4*)(kpp + 4);
      ushort4 u0, u1;
      u0.x = f2bf(f0.x); u0.y = f2bf(f0.y); u0.z = f2bf(f0.z); u0.w = f2bf(f0.w);
      u1.x = f2bf(f1.x); u1.y = f2bf(f1.y); u1.z = f2bf(f1.z); u1.w = f2bf(f1.w);
      *(ushort4*)&kp_[krow * 36 + kc8] = u0;
      *(ushort4*)&kp_[krow * 36 + kc8 + 4] = u1;
    }
    __syncthreads();
    const int kt0 = (kti + g * 8) << 6;

    // ---- QK^T: B-frags straight from global (same-XCD L2) ----
    f32x4 sc4[4];
#pragma unroll
    for (int t4 = 0; t4 < 4; ++t4) {
      f32x4 c = z;
      c = MFMA16(aQ[0], ldb16x8(kbase + (size_t)(kt0 + t4 * 16 + ln) * 64 + qd * 8), c);
      c = MFMA16(aQ[1], ldb16x8(kbase + (size_t)(kt0 + t4 * 16 + ln) * 64 + 32 + qd * 8), c);
      sc4[t4] = c;
    }

    // ---- bias + scale + mask + exp; u64 vdw scatter; P -> pbuf ----
    unsigned char* pt_ = pkt + g * 5120;
    unsigned short* kp_ = kpws + g * 2304;
#pragma unroll
    for (int r = 0; r < 4; ++r) {
#pragma unroll
      for (int t4 = 0; t4 < 4; ++t4) {
        int row_l = ws4 * 16 + qd * 4 + r;
        int kl = t4 * 16 + ln;
        unsigned um = pt_[row_l * 80 + kl];
        int rd = um & 31;
        float s = (sc4[t4][r] + b2f(q32s[row_l * 36 + rd]) + b2f(kp_[kl * 36 + rd])) * 0.125f;
        float p = (um & 0x80u) ? 0.f : __expf(s);
        atomicAdd(&vdwm64[ws4 * 576 + (qd * 4 + r) * 36 + rd],
                  (unsigned long long)(p * 67108864.0f));     // Q = 2^26, native ds_add
        pbuf[w * 1152 + (qd * 4 + r) * 72 + kl] = f2bf(p);
      }
    }

    // ---- PV: O += P(16x64) @ V(64x64); V-frags from global (L2) ----
    bf16x8 a0 = ldb16x8(&pbuf[w * 1152 + ln * 72 + qd * 8]);
    bf16x8 a1 = ldb16x8(&pbuf[w * 1152 + ln * 72 + 32 + qd * 8]);
#pragma unroll
    for (int dt = 0; dt < 4; ++dt) {
      acc[dt] = MFMA16(a0, ldb16x8(vbase + (size_t)(dt * 16 + ln) * 1024 + kt0 + qd * 8), acc[dt]);
      acc[dt] = MFMA16(a1, ldb16x8(vbase + (size_t)(dt * 16 + ln) * 1024 + kt0 + 32 + qd * 8), acc[dt]);
    }
    __syncthreads();
  }

  // ---- endgame: vest staged by g0 threads, vdwb built by g1 waves ----
  if (t < 256) {
    int n = t >> 3, d0 = (t & 7) << 3;
    const float* src = v_emb + ((size_t)n << 9) + (h << 6) + d0;
    float4 f0 = *(const float4*)src;
    float4 f1 = *(const float4*)(src + 4);
    vest[(d0 + 0) * 40 + n] = f2bf(f0.x); vest[(d0 + 1) * 40 + n] = f2bf(f0.y);
    vest[(d0 + 2) * 40 + n] = f2bf(f0.z); vest[(d0 + 3) * 40 + n] = f2bf(f0.w);
    vest[(d0 + 4) * 40 + n] = f2bf(f1.x); vest[(d0 + 5) * 40 + n] = f2bf(f1.y);
    vest[(d0 + 6) * 40 + n] = f2bf(f1.z); vest[(d0 + 7) * 40 + n] = f2bf(f1.w);
  } else {
    int row = lane >> 2, n0 = (lane & 3) << 3;
    float vv[8];
#pragma unroll
    for (int j = 0; j < 8; ++j)
      vv[j] = (float)vdwm64[ws4 * 576 + row * 36 + n0 + j] * 1.4901161193847656e-8f;
    ushort4 u0, u1;
    u0.x = f2bf(vv[0]); u0.y = f2bf(vv[1]); u0.z = f2bf(vv[2]); u0.w = f2bf(vv[3]);
    u1.x = f2bf(vv[4]); u1.y = f2bf(vv[5]); u1.z = f2bf(vv[6]); u1.w = f2bf(vv[7]);
    *(ushort4*)&vdwb[ws4 * 640 + row * 40 + n0] = u0;
    *(ushort4*)&vdwb[ws4 * 640 + row * 40 + n0 + 4] = u1;
  }
  __syncthreads();

  if (g == 1) {  // add vdw @ v_emb into g1 partial, publish partial O
    bf16x8 av = ldb16x8(&vdwb[ws4 * 640 + ln * 40 + qd * 8]);
#pragma unroll
    for (int dt = 0; dt < 4; ++dt)
      acc[dt] = MFMA16(av, ldb16x8(&vest[(dt * 16 + ln) * 40 + qd * 8]), acc[dt]);
#pragma unroll
    for (int r = 0; r < 4; ++r)
#pragma unroll
      for (int dt = 0; dt < 4; ++dt)
        accbuf[ws4 * 1088 + (qd * 4 + r) * 68 + dt * 16 + ln] = acc[dt][r];
  }
  __syncthreads();

  if (g == 0) {  // combine, normalize, store bf16
    float inv[4];
#pragma unroll
    for (int r = 0; r < 4; ++r) {
      unsigned long long lu = 0ull;
#pragma unroll
      for (int n = 0; n < 32; ++n)
        lu += vdwm64[ws4 * 576 + (qd * 4 + r) * 36 + n];
      inv[r] = 67108864.0f / (float)lu;    // = 1 / (lu * 2^-26)
    }
    unsigned short* obase =
        attn16 + ((size_t)(b * 512 + qb + ws4 * 16 + qd * 4)) * 512 + (h << 6);
#pragma unroll
    for (int r = 0; r < 4; ++r)
#pragma unroll
      for (int dt = 0; dt < 4; ++dt) {
        float v = (acc[dt][r] + accbuf[ws4 * 1088 + (qd * 4 + r) * 68 + dt * 16 + ln]) * inv[r];
        obase[(size_t)r * 512 + dt * 16 + ln] = f2bf(v);
      }
  }
}

// ---------------------------------------------------------------------------
extern "C" void kernel_launch(void* const* d_in, const int* in_sizes, int n_in,
                              void* d_out, int out_size, void* d_ws, size_t ws_size,
                              hipStream_t stream) {
  const float* x = (const float*)d_in[0];
  const int* rel = (const int*)d_in[1];
  const unsigned char* mask = (const unsigned char*)d_in[2];
  const float* qpe = (const float*)d_in[3];
  const float* kpe = (const float*)d_in[4];
  const float* vpe = (const float*)d_in[5];
  const float* Wq = (const float*)d_in[6];
  const float* Wk = (const float*)d_in[7];
  const float* Wv = (const float*)d_in[8];
  const float* Wo = (const float*)d_in[9];
  float* out = (float*)d_out;

  float* ws = (float*)d_ws;
  float* qpw = ws;                                   // 1,048,576 f
  float* kpw = qpw + 1048576;                        // 2,097,152 f
  unsigned short* kb16 = (unsigned short*)(kpw + 2097152);   // 4,194,304 u16
  unsigned short* vT16 = kb16 + 4194304;             // 4,194,304 u16
  unsigned short* q16h = vT16 + 4194304;             // 2,097,152 u16
  unsigned short* attn16 = q16h + 2097152;           // 2,097,152 u16
  unsigned short* x16 = attn16 + 2097152;            // 2,097,152 u16
  unsigned short* w16q = x16 + 2097152;              //   262,144 u16
  unsigned short* w16k = w16q + 262144;              //   524,288 u16
  unsigned short* w16v = w16k + 524288;              //   524,288 u16
  unsigned short* w16o = w16v + 524288;              //   262,144 u16
  unsigned char* pk8 = (unsigned char*)(w16o + 262144);  // 4,194,304 u8 -> ~49 MB

  pack_k<<<1024, 256, 0, stream>>>(rel, mask, pk8);
  cvt5_k<<<3584, 256, 0, stream>>>(x, Wq, Wk, Wv, Wo, x16, w16q, w16k, w16v, w16o);
  gemm16_k<1><<<dim3(8, 64), 256, 0, stream>>>(x16, w16q, q16h, 4096, 512, 512);
  gemm16_k<2><<<dim3(16, 64), 256, 0, stream>>>(x16, w16k, kb16, 4096, 1024, 512);
  gemm16_k<3><<<dim3(16, 64), 256, 0, stream>>>(x16, w16v, vT16, 4096, 1024, 512);
  posw16_k<<<8 * 8 * 8, 256, 0, stream>>>(q16h, qpe, qpw, 512);
  posw16_k<<<8 * 8 * 16, 256, 0, stream>>>(kb16, kpe, kpw, 1024);
  attn5_k<<<512, 512, 0, stream>>>(q16h, kb16, vT16, qpw, kpw, pk8, vpe, attn16);
  gemm16_k<0><<<dim3(8, 64), 256, 0, stream>>>(attn16, w16o, out, 4096, 512, 512);
}

// Round 8
// 220.795 us; speedup vs baseline: 2.1405x; 1.0784x over previous
//
#include <hip/hip_runtime.h>
#include <math.h>

#define Bc 8
#define Sc 512
#define Hc 512
#define NHc 8
#define HDc 64
#define DISc 32
#define S2c 1024

typedef __attribute__((ext_vector_type(8))) short bf16x8;
typedef __attribute__((ext_vector_type(4))) float f32x4;
#define MFMA16(a, b, c) __builtin_amdgcn_mfma_f32_16x16x32_bf16(a, b, c, 0, 0, 0)

__device__ __forceinline__ unsigned short f2bf(float f) {
  unsigned u = __float_as_uint(f);
  return (unsigned short)((u + 0x7fffu + ((u >> 16) & 1u)) >> 16);  // RNE
}
__device__ __forceinline__ float b2f(unsigned short u) {
  return __uint_as_float((unsigned)u << 16);
}
__device__ __forceinline__ bf16x8 ldb16x8(const unsigned short* p) {
  union { uint4 u; bf16x8 s; } cv;
  cv.u = *(const uint4*)p;
  return cv.s;
}

// ---------------------------------------------------------------------------
// fp32 -> bf16 conversions. Wq is pre-scaled by 0.125 (exact exponent shift)
// so QK^T comes out of the attention MFMA already divided by 8.
// ---------------------------------------------------------------------------
__global__ __launch_bounds__(256) void cvt5_k(
    const float* __restrict__ x, const float* __restrict__ wq,
    const float* __restrict__ wk, const float* __restrict__ wv,
    const float* __restrict__ wo, unsigned short* __restrict__ x16,
    unsigned short* __restrict__ w16q, unsigned short* __restrict__ w16k,
    unsigned short* __restrict__ w16v, unsigned short* __restrict__ w16o) {
  int i = blockIdx.x * 256 + threadIdx.x;
  const float* src; unsigned short* dst; int off; float sc = 1.f;
  if (i < 524288)      { src = x;  dst = x16;  off = i; }
  else if (i < 589824) { src = wq; dst = w16q; off = i - 524288; sc = 0.125f; }
  else if (i < 720896) { src = wk; dst = w16k; off = i - 589824; }
  else if (i < 851968) { src = wv; dst = w16v; off = i - 720896; }
  else                 { src = wo; dst = w16o; off = i - 851968; }
  float4 v = ((const float4*)src)[off];
  ushort4 u;
  u.x = f2bf(v.x * sc); u.y = f2bf(v.y * sc);
  u.z = f2bf(v.z * sc); u.w = f2bf(v.w * sc);
  ((ushort4*)dst)[off] = u;
}

// ---------------------------------------------------------------------------
// Pack rel (int32 0..31) + mask (u8) -> u8 (rd | m<<7).
// ---------------------------------------------------------------------------
__global__ __launch_bounds__(256) void pack_k(const int* __restrict__ rel,
                                              const unsigned char* __restrict__ mask,
                                              unsigned char* __restrict__ pk8) {
  int i = blockIdx.x * 256 + threadIdx.x;
  const int* rp = rel + i * 16;
  uint4 mu = *(const uint4*)(mask + i * 16);
  const unsigned char* mb = (const unsigned char*)&mu;
  uint4 o;
  unsigned* ow = (unsigned*)&o;
#pragma unroll
  for (int g = 0; g < 4; ++g) {
    int4 r4 = ((const int4*)rp)[g];
    unsigned b0 = ((unsigned)r4.x & 31u) | (mb[g * 4 + 0] ? 0x80u : 0u);
    unsigned b1 = ((unsigned)r4.y & 31u) | (mb[g * 4 + 1] ? 0x80u : 0u);
    unsigned b2 = ((unsigned)r4.z & 31u) | (mb[g * 4 + 2] ? 0x80u : 0u);
    unsigned b3 = ((unsigned)r4.w & 31u) | (mb[g * 4 + 3] ? 0x80u : 0u);
    ow[g] = b0 | (b1 << 8) | (b2 << 16) | (b3 << 24);
  }
  *(uint4*)(pk8 + i * 16) = o;
}

// ---------------------------------------------------------------------------
// Fold pos-embeddings into the projection weights:
//   Wqpw[h*32+n][c]        = 1/8 * sum_d qpe[n][h*64+d] * Wq[h*64+d][c]
//   Wkpw[e*256+h*32+n][c]  = 1/8 * sum_d kpe[n][h*64+d] * Wk[e*512+h*64+d][c]
// fp32 math from original fp32 inputs, bf16 out. grid 96 = 24 units x 4 c-chunks.
// ---------------------------------------------------------------------------
__global__ __launch_bounds__(256) void wemb_k(
    const float* __restrict__ qpe, const float* __restrict__ kpe,
    const float* __restrict__ Wq, const float* __restrict__ Wk,
    unsigned short* __restrict__ wqp, unsigned short* __restrict__ wkp) {
  const int bid = blockIdx.x;
  const int cc = bid & 3, unit = bid >> 2;
  const int c0 = cc << 7;
  const int t = threadIdx.x;
  const float* emb; const float* Wsrc; unsigned short* outp; int rowbase, h;
  if (unit < 8) {
    h = unit; emb = qpe; Wsrc = Wq + (size_t)(h * 64) * 512; outp = wqp; rowbase = h * 32;
  } else {
    int u = unit - 8; int e = u >> 3; h = u & 7;
    emb = kpe; Wsrc = Wk + (size_t)(e * 512 + h * 64) * 512; outp = wkp;
    rowbase = e * 256 + h * 32;
  }
  __shared__ float es[32][65];
  __shared__ float wsh[64][132];
  {
    int n = t >> 3, d4 = (t & 7) << 3;
    float4 v0 = *(const float4*)(emb + (size_t)n * 512 + h * 64 + d4);
    float4 v1 = *(const float4*)(emb + (size_t)n * 512 + h * 64 + d4 + 4);
    *(float4*)&es[n][d4] = v0;
    *(float4*)&es[n][d4 + 4] = v1;
  }
#pragma unroll
  for (int p = 0; p < 8; ++p) {
    int slot = t + (p << 8);
    int d = slot >> 5, c4 = (slot & 31) << 2;
    *(float4*)&wsh[d][c4] = *(const float4*)(Wsrc + (size_t)d * 512 + c0 + c4);
  }
  __syncthreads();
  const int n = t >> 3, cb = (t & 7) << 4;
  float acc[16] = {};
#pragma unroll
  for (int d = 0; d < 64; ++d) {
    float ev = es[n][d];
    float4 w0 = *(const float4*)&wsh[d][cb];
    float4 w1 = *(const float4*)&wsh[d][cb + 4];
    float4 w2 = *(const float4*)&wsh[d][cb + 8];
    float4 w3 = *(const float4*)&wsh[d][cb + 12];
    acc[0] = fmaf(ev, w0.x, acc[0]);   acc[1] = fmaf(ev, w0.y, acc[1]);
    acc[2] = fmaf(ev, w0.z, acc[2]);   acc[3] = fmaf(ev, w0.w, acc[3]);
    acc[4] = fmaf(ev, w1.x, acc[4]);   acc[5] = fmaf(ev, w1.y, acc[5]);
    acc[6] = fmaf(ev, w1.z, acc[6]);   acc[7] = fmaf(ev, w1.w, acc[7]);
    acc[8] = fmaf(ev, w2.x, acc[8]);   acc[9] = fmaf(ev, w2.y, acc[9]);
    acc[10] = fmaf(ev, w2.z, acc[10]); acc[11] = fmaf(ev, w2.w, acc[11]);
    acc[12] = fmaf(ev, w3.x, acc[12]); acc[13] = fmaf(ev, w3.y, acc[13]);
    acc[14] = fmaf(ev, w3.z, acc[14]); acc[15] = fmaf(ev, w3.w, acc[15]);
  }
  unsigned short* orow = outp + (size_t)(rowbase + n) * 512 + c0 + cb;
#pragma unroll
  for (int j = 0; j < 16; ++j) orow[j] = f2bf(acc[j] * 0.125f);
}

// ---------------------------------------------------------------------------
// bf16 MFMA GEMM, 64x64 tile, BK=64, LDS stride 72 (conflict-free frag reads),
// register-pipelined staging. B = concat(B1[0:nsplit), B2[nsplit:N)) row-major [N][K].
// MODE 0: fp32 out1[m*N+n]
// MODE 1: n<512 -> q16h[b,h,s,d] (pre-scaled via Wq); n>=512 -> qpw16[b,h,s,32]
// MODE 2: n<1024 -> kb16[b,h,k2,d]; n>=1024 -> kpw16[b,h,k2,32]
// MODE 3: vT16[b,h,d,k2]
// ---------------------------------------------------------------------------
template <int MODE>
__global__ __launch_bounds__(256, 4) void gemm16_k(
    const unsigned short* __restrict__ A, const unsigned short* __restrict__ B1,
    const unsigned short* __restrict__ B2, void* __restrict__ out1,
    void* __restrict__ out2, int M, int N, int K, int nsplit) {
  const int t = threadIdx.x;
  const int w = t >> 6, lane = t & 63, ln = lane & 15, qd = lane >> 4;
  const int wm = (w >> 1) << 5, wn = (w & 1) << 5;
  const int m0 = blockIdx.y << 6, n0 = blockIdx.x << 6;
  __shared__ unsigned short As[64 * 72];
  __shared__ unsigned short Bs[64 * 72];
  const bool reg1 = (n0 < nsplit);
  const unsigned short* Bb =
      reg1 ? B1 + (size_t)n0 * K : B2 + (size_t)(n0 - nsplit) * K;
  const int r0 = t >> 3, c8 = (t & 7) << 3;
  const unsigned short* ga = A + (size_t)(m0 + r0) * K + c8;
  const unsigned short* gb = Bb + (size_t)r0 * K + c8;
  const size_t half = (size_t)32 * K;
  uint4 va0 = *(const uint4*)ga, va1 = *(const uint4*)(ga + half);
  uint4 vb0 = *(const uint4*)gb, vb1 = *(const uint4*)(gb + half);
  f32x4 z = {0.f, 0.f, 0.f, 0.f};
  f32x4 acc[2][2] = {{z, z}, {z, z}};
  for (int k0 = 0; k0 < K; k0 += 64) {
    *(uint4*)&As[r0 * 72 + c8] = va0;
    *(uint4*)&As[(r0 + 32) * 72 + c8] = va1;
    *(uint4*)&Bs[r0 * 72 + c8] = vb0;
    *(uint4*)&Bs[(r0 + 32) * 72 + c8] = vb1;
    __syncthreads();
    if (k0 + 64 < K) {
      va0 = *(const uint4*)(ga + k0 + 64);
      va1 = *(const uint4*)(ga + half + k0 + 64);
      vb0 = *(const uint4*)(gb + k0 + 64);
      vb1 = *(const uint4*)(gb + half + k0 + 64);
    }
#pragma unroll
    for (int kk = 0; kk < 64; kk += 32) {
      bf16x8 a0 = ldb16x8(&As[(wm + ln) * 72 + kk + qd * 8]);
      bf16x8 a1 = ldb16x8(&As[(wm + 16 + ln) * 72 + kk + qd * 8]);
      bf16x8 b0 = ldb16x8(&Bs[(wn + ln) * 72 + kk + qd * 8]);
      bf16x8 b1 = ldb16x8(&Bs[(wn + 16 + ln) * 72 + kk + qd * 8]);
      acc[0][0] = MFMA16(a0, b0, acc[0][0]);
      acc[0][1] = MFMA16(a0, b1, acc[0][1]);
      acc[1][0] = MFMA16(a1, b0, acc[1][0]);
      acc[1][1] = MFMA16(a1, b1, acc[1][1]);
    }
    __syncthreads();
  }
#pragma unroll
  for (int tm = 0; tm < 2; ++tm)
#pragma unroll
    for (int tn = 0; tn < 2; ++tn)
#pragma unroll
      for (int r = 0; r < 4; ++r) {
        int m = m0 + wm + tm * 16 + qd * 4 + r;
        int n = n0 + wn + tn * 16 + ln;
        float v = acc[tm][tn][r];
        int bb = m >> 9, s = m & 511;
        if (MODE == 0) {
          ((float*)out1)[(size_t)m * N + n] = v;
        } else if (MODE == 3) {
          int e = n >> 9, hh = (n >> 6) & 7, d = n & 63;
          int k2 = 2 * s + e;
          ((unsigned short*)out1)[((size_t)(bb * 8 + hh) * 64 + d) * 1024 + k2] = f2bf(v);
        } else if (MODE == 1) {
          if (reg1) {
            int hh = (n >> 6) & 7, d = n & 63;
            ((unsigned short*)out1)[((size_t)(bb * 8 + hh) * 512 + s) * 64 + d] = f2bf(v);
          } else {
            int n2 = n - 512, hh = n2 >> 5, nn = n2 & 31;
            ((unsigned short*)out2)[((size_t)(bb * 8 + hh) * 512 + s) * 32 + nn] = f2bf(v);
          }
        } else {  // MODE 2
          if (reg1) {
            int e = n >> 9, hh = (n >> 6) & 7, d = n & 63;
            int k2 = 2 * s + e;
            ((unsigned short*)out1)[((size_t)(bb * 8 + hh) * 1024 + k2) * 64 + d] = f2bf(v);
          } else {
            int n2 = n - 1024, e = n2 >> 8, hh = (n2 >> 5) & 7, nn = n2 & 31;
            int k2 = 2 * s + e;
            ((unsigned short*)out2)[((size_t)(bb * 8 + hh) * 1024 + k2) * 32 + nn] = f2bf(v);
          }
        }
      }
}

// ---------------------------------------------------------------------------
// MFMA attention. u64 fixed-point vdw histogram (native ds_add_u64 — the R7
// fix). bf16 bias tables staged as raw uint4 copies; scale folded into q/tables;
// next-kt staging registers prefetched under the MFMA work. XCD-affine grid.
// ---------------------------------------------------------------------------
__global__ __launch_bounds__(512, 4) void attn6_k(
    const unsigned short* __restrict__ q16h, const unsigned short* __restrict__ kb16,
    const unsigned short* __restrict__ vT16, const unsigned short* __restrict__ qpw16,
    const unsigned short* __restrict__ kpw16, const unsigned char* __restrict__ pk8,
    const float* __restrict__ v_emb, unsigned short* __restrict__ attn16) {
  const int bid = blockIdx.x;
  const int b = bid & 7;                 // XCD-affine: bid%8 == b
  const int h = (bid >> 3) & 7;
  const int qb = ((bid >> 6) & 7) << 6;
  const int t = threadIdx.x;
  const int w = t >> 6;
  const int g = w >> 2;
  const int ws4 = w & 3;
  const int lane = t & 63;
  const int ln = lane & 15;
  const int qd = lane >> 4;

  __shared__ __align__(16) char smem[60928];
  unsigned char*  pkt  = (unsigned char*)smem;                // 2 x (64x80) u8
  unsigned short* kpws = (unsigned short*)(smem + 10240);     // 2 x (64x36) u16
  unsigned short* q32s = (unsigned short*)(smem + 19456);     // 64x36 u16
  unsigned short* pbuf = (unsigned short*)(smem + 24064);     // 8 x (16x72) u16
  unsigned long long* vdwm64 = (unsigned long long*)(smem + 42496); // 4 x (16x36) u64
  // endgame aliases (source regions dead by then):
  float*          accbuf = (float*)smem;                      // 4 x (16x68) f
  unsigned short* vest   = (unsigned short*)(smem + 24064);   // 64x40 u16
  unsigned short* vdwb   = (unsigned short*)(smem + 29184);   // 4 x (16x40) u16

  for (int i = t; i < 4 * 16 * 36; i += 512) vdwm64[i] = 0ull;
  if (t < 256) {  // q32s: 64 q x 32 n bf16, straight copy
    int row = t >> 2, c8 = (t & 3) << 3;
    *(uint4*)&q32s[row * 36 + c8] =
        *(const uint4*)(qpw16 + ((size_t)((b * 8 + h) * 512 + qb) + row) * 32 + c8);
  }
  const unsigned short* kbase = kb16 + (size_t)(b * 8 + h) * 65536;
  const unsigned short* vbase = vT16 + (size_t)(b * 8 + h) * 65536;
  bf16x8 aQ[2];
  {
    const unsigned short* qsrc =
        q16h + ((size_t)((b * 8 + h) * 512 + qb + ws4 * 16 + ln)) * 64;
    aQ[0] = ldb16x8(qsrc + qd * 8);
    aQ[1] = ldb16x8(qsrc + 32 + qd * 8);
  }
  f32x4 z = {0.f, 0.f, 0.f, 0.f};
  f32x4 acc[4] = {z, z, z, z};

  // staging addresses (thread-fixed): squad gg = t>>8 stages for kt-half gg
  const int u = t & 255, gg = t >> 8;
  const int qr = u >> 2, cg = (u & 3) << 4;        // pkt slot (bytes)
  const int kc8 = (u & 3) << 3;                    // kpw slot (u16)
  const unsigned char* pks = pk8 + ((size_t)(b * 512 + qb + qr)) * 1024 + (gg << 9);
  const unsigned short* kps =
      kpw16 + ((size_t)((b * 8 + h) * 1024) + (gg << 9) + qr) * 32 + kc8;
  unsigned char* pt_w = pkt + gg * 5120 + qr * 80 + cg;
  unsigned short* kp_w = kpws + gg * 2304 + qr * 36 + kc8;

  uint4 pv = *(const uint4*)(pks + cg);
  uint4 kv = *(const uint4*)kps;

  for (int kti = 0; kti < 8; ++kti) {
    *(uint4*)pt_w = pv;
    *(uint4*)kp_w = kv;
    __syncthreads();
    if (kti < 7) {  // prefetch next kt's staging under the MFMA work
      pv = *(const uint4*)(pks + ((kti + 1) << 6) + cg);
      kv = *(const uint4*)(kps + ((size_t)(kti + 1) << 11));   // (kti+1)*64*32
    }
    const int kt0 = (kti + g * 8) << 6;

    // ---- QK^T: B-frags straight from global (same-XCD L2) ----
    f32x4 sc4[4];
#pragma unroll
    for (int t4 = 0; t4 < 4; ++t4) {
      f32x4 c = z;
      c = MFMA16(aQ[0], ldb16x8(kbase + (size_t)(kt0 + t4 * 16 + ln) * 64 + qd * 8), c);
      c = MFMA16(aQ[1], ldb16x8(kbase + (size_t)(kt0 + t4 * 16 + ln) * 64 + 32 + qd * 8), c);
      sc4[t4] = c;
    }

    // ---- bias + mask + exp; u64 vdw scatter; P -> pbuf ----
    unsigned char* pt_ = pkt + g * 5120;
    unsigned short* kp_ = kpws + g * 2304;
#pragma unroll
    for (int r = 0; r < 4; ++r) {
#pragma unroll
      for (int t4 = 0; t4 < 4; ++t4) {
        int row_l = ws4 * 16 + qd * 4 + r;
        int kl = t4 * 16 + ln;
        unsigned um = pt_[row_l * 80 + kl];
        int rd = um & 31;
        float s = sc4[t4][r] + b2f(q32s[row_l * 36 + rd]) + b2f(kp_[kl * 36 + rd]);
        float p = (um & 0x80u) ? 0.f : __expf(s);
        atomicAdd(&vdwm64[ws4 * 576 + (qd * 4 + r) * 36 + rd],
                  (unsigned long long)(p * 67108864.0f));     // Q = 2^26
        pbuf[w * 1152 + (qd * 4 + r) * 72 + kl] = f2bf(p);
      }
    }

    // ---- PV: O += P(16x64) @ V(64x64) ----
    bf16x8 a0 = ldb16x8(&pbuf[w * 1152 + ln * 72 + qd * 8]);
    bf16x8 a1 = ldb16x8(&pbuf[w * 1152 + ln * 72 + 32 + qd * 8]);
#pragma unroll
    for (int dt = 0; dt < 4; ++dt) {
      acc[dt] = MFMA16(a0, ldb16x8(vbase + (size_t)(dt * 16 + ln) * 1024 + kt0 + qd * 8), acc[dt]);
      acc[dt] = MFMA16(a1, ldb16x8(vbase + (size_t)(dt * 16 + ln) * 1024 + kt0 + 32 + qd * 8), acc[dt]);
    }
    __syncthreads();
  }

  // ---- endgame: vest staged by g0 threads, vdwb built by g1 waves ----
  if (t < 256) {
    int n = t >> 3, d0 = (t & 7) << 3;
    const float* src = v_emb + ((size_t)n << 9) + (h << 6) + d0;
    float4 f0 = *(const float4*)src;
    float4 f1 = *(const float4*)(src + 4);
    vest[(d0 + 0) * 40 + n] = f2bf(f0.x); vest[(d0 + 1) * 40 + n] = f2bf(f0.y);
    vest[(d0 + 2) * 40 + n] = f2bf(f0.z); vest[(d0 + 3) * 40 + n] = f2bf(f0.w);
    vest[(d0 + 4) * 40 + n] = f2bf(f1.x); vest[(d0 + 5) * 40 + n] = f2bf(f1.y);
    vest[(d0 + 6) * 40 + n] = f2bf(f1.z); vest[(d0 + 7) * 40 + n] = f2bf(f1.w);
  } else {
    int row = lane >> 2, n0 = (lane & 3) << 3;
    float vv[8];
#pragma unroll
    for (int j = 0; j < 8; ++j)
      vv[j] = (float)vdwm64[ws4 * 576 + row * 36 + n0 + j] * 1.4901161193847656e-8f;
    ushort4 u0, u1;
    u0.x = f2bf(vv[0]); u0.y = f2bf(vv[1]); u0.z = f2bf(vv[2]); u0.w = f2bf(vv[3]);
    u1.x = f2bf(vv[4]); u1.y = f2bf(vv[5]); u1.z = f2bf(vv[6]); u1.w = f2bf(vv[7]);
    *(ushort4*)&vdwb[ws4 * 640 + row * 40 + n0] = u0;
    *(ushort4*)&vdwb[ws4 * 640 + row * 40 + n0 + 4] = u1;
  }
  __syncthreads();

  if (g == 1) {
    bf16x8 av = ldb16x8(&vdwb[ws4 * 640 + ln * 40 + qd * 8]);
#pragma unroll
    for (int dt = 0; dt < 4; ++dt)
      acc[dt] = MFMA16(av, ldb16x8(&vest[(dt * 16 + ln) * 40 + qd * 8]), acc[dt]);
#pragma unroll
    for (int r = 0; r < 4; ++r)
#pragma unroll
      for (int dt = 0; dt < 4; ++dt)
        accbuf[ws4 * 1088 + (qd * 4 + r) * 68 + dt * 16 + ln] = acc[dt][r];
  }
  __syncthreads();

  if (g == 0) {
    float inv[4];
#pragma unroll
    for (int r = 0; r < 4; ++r) {
      unsigned long long lu = 0ull;
#pragma unroll
      for (int n = 0; n < 32; ++n)
        lu += vdwm64[ws4 * 576 + (qd * 4 + r) * 36 + n];
      inv[r] = 67108864.0f / (float)lu;
    }
    unsigned short* obase =
        attn16 + ((size_t)(b * 512 + qb + ws4 * 16 + qd * 4)) * 512 + (h << 6);
#pragma unroll
    for (int r = 0; r < 4; ++r)
#pragma unroll
      for (int dt = 0; dt < 4; ++dt) {
        float v = (acc[dt][r] + accbuf[ws4 * 1088 + (qd * 4 + r) * 68 + dt * 16 + ln]) * inv[r];
        obase[(size_t)r * 512 + dt * 16 + ln] = f2bf(v);
      }
  }
}

// ---------------------------------------------------------------------------
extern "C" void kernel_launch(void* const* d_in, const int* in_sizes, int n_in,
                              void* d_out, int out_size, void* d_ws, size_t ws_size,
                              hipStream_t stream) {
  const float* x = (const float*)d_in[0];
  const int* rel = (const int*)d_in[1];
  const unsigned char* mask = (const unsigned char*)d_in[2];
  const float* qpe = (const float*)d_in[3];
  const float* kpe = (const float*)d_in[4];
  const float* vpe = (const float*)d_in[5];
  const float* Wq = (const float*)d_in[6];
  const float* Wk = (const float*)d_in[7];
  const float* Wv = (const float*)d_in[8];
  const float* Wo = (const float*)d_in[9];
  float* out = (float*)d_out;

  unsigned short* u = (unsigned short*)d_ws;
  unsigned short* x16    = u;                    // 2,097,152
  unsigned short* w16q   = x16 + 2097152;        //   262,144
  unsigned short* w16k   = w16q + 262144;        //   524,288
  unsigned short* w16v   = w16k + 524288;        //   524,288
  unsigned short* w16o   = w16v + 524288;        //   262,144
  unsigned short* wqp16  = w16o + 262144;        //   131,072  (256x512)
  unsigned short* wkp16  = wqp16 + 131072;       //   262,144  (512x512)
  unsigned short* q16h   = wkp16 + 262144;       // 2,097,152
  unsigned short* qpw16  = q16h + 2097152;       // 1,048,576  [b,h,s,32]
  unsigned short* kb16   = qpw16 + 1048576;      // 4,194,304
  unsigned short* kpw16  = kb16 + 4194304;       // 2,097,152  [b,h,k2,32]
  unsigned short* vT16   = kpw16 + 2097152;      // 4,194,304
  unsigned short* attn16 = vT16 + 4194304;       // 2,097,152
  unsigned char* pk8 = (unsigned char*)(attn16 + 2097152);  // 4 MB  -> ~44 MB total

  pack_k<<<1024, 256, 0, stream>>>(rel, mask, pk8);
  cvt5_k<<<3584, 256, 0, stream>>>(x, Wq, Wk, Wv, Wo, x16, w16q, w16k, w16v, w16o);
  wemb_k<<<96, 256, 0, stream>>>(qpe, kpe, Wq, Wk, wqp16, wkp16);
  gemm16_k<1><<<dim3(12, 64), 256, 0, stream>>>(x16, w16q, wqp16, q16h, qpw16,
                                                4096, 768, 512, 512);
  gemm16_k<2><<<dim3(24, 64), 256, 0, stream>>>(x16, w16k, wkp16, kb16, kpw16,
                                                4096, 1536, 512, 1024);
  gemm16_k<3><<<dim3(16, 64), 256, 0, stream>>>(x16, w16v, nullptr, vT16, nullptr,
                                                4096, 1024, 512, 1024);
  attn6_k<<<512, 512, 0, stream>>>(q16h, kb16, vT16, qpw16, kpw16, pk8, vpe, attn16);
  gemm16_k<0><<<dim3(8, 64), 256, 0, stream>>>(attn16, w16o, nullptr, out, nullptr,
                                               4096, 512, 512, 512);
}